// Round 9
// baseline (266.855 us; speedup 1.0000x reference)
//
#include <hip/hip_runtime.h>
#include <hip/hip_bf16.h>
#include <math.h>

#define NROWS 8192
#define DIN   512
#define DHID  256
#define DOUT  128
#define LOG2E 1.4426950408889634f

typedef unsigned short ushort_t;
typedef __attribute__((ext_vector_type(8))) short bf16x8;
typedef __attribute__((ext_vector_type(4))) float f32x4;

#if defined(__has_builtin)
#  if __has_builtin(__builtin_amdgcn_exp2f)
#    define FAST_EXP2(x) __builtin_amdgcn_exp2f(x)
#  else
#    define FAST_EXP2(x) exp2f(x)
#  endif
#else
#  define FAST_EXP2(x) exp2f(x)
#endif

__device__ __forceinline__ short f2bf(float x) {
  __hip_bfloat16 h = __float2bfloat16(x);
  return *(short*)&h;
}

__device__ __forceinline__ bf16x8 cvt8(float4 lo, float4 hi) {
  bf16x8 r;
  r[0] = f2bf(lo.x); r[1] = f2bf(lo.y); r[2] = f2bf(lo.z); r[3] = f2bf(lo.w);
  r[4] = f2bf(hi.x); r[5] = f2bf(hi.y); r[6] = f2bf(hi.z); r[7] = f2bf(hi.w);
  return r;
}

// async 16B global->LDS copy: lds dest = wave-uniform base + lane*16.
__device__ __forceinline__ void dma16(const void* g, void* l) {
  __builtin_amdgcn_global_load_lds(
      (const __attribute__((address_space(1))) unsigned int*)g,
      (__attribute__((address_space(3))) unsigned int*)l, 16, 0, 0);
}

// ---------------------------------------------------------------------------
// Weight prep (all 3 heads) + workspace zeroing (replaces hipMemsetAsync).
// W1 (512x256)->w1t (256x512), W2 (256x128)->w2t (128x256), fp32 -> bf16,
// transposed so k is contiguous. grid (640, 3). z==0, bx<163 blocks also
// zero the 41728-float accumulator region (163*256 == 41728 exactly).
// ---------------------------------------------------------------------------
__global__ __launch_bounds__(256) void prep_w_kernel(
    const float* __restrict__ W1_0, const float* __restrict__ W1_1,
    const float* __restrict__ W1_2,
    const float* __restrict__ W2_0, const float* __restrict__ W2_1,
    const float* __restrict__ W2_2,
    ushort_t* __restrict__ w1t3, ushort_t* __restrict__ w2t3,
    float* __restrict__ zero_region)
{
  const int z = blockIdx.y;
  if (z == 0 && blockIdx.x < 163)
    zero_region[blockIdx.x * 256 + threadIdx.x] = 0.0f;
  const float* W1 = z == 0 ? W1_0 : (z == 1 ? W1_1 : W1_2);
  const float* W2 = z == 0 ? W2_0 : (z == 1 ? W2_1 : W2_2);
  int idx = blockIdx.x * 256 + threadIdx.x;
  if (idx < DHID * DIN) {
    int n = idx >> 9, k = idx & (DIN - 1);
    w1t3[(size_t)z * DHID * DIN + idx] = f2bf(W1[(size_t)k * DHID + n]);
  } else {
    int j = idx - DHID * DIN;
    int n = j >> 8, k = j & (DHID - 1);
    w2t3[(size_t)z * DOUT * DHID + j] = f2bf(W2[(size_t)k * DOUT + n]);
  }
}

// ---------------------------------------------------------------------------
// Fused MLP (all heads): y = (relu(x@W1+b1))@W2 + b2, fp32 + col stats.
// Block = 32 rows; phase 1 = DMA-staged K-loop (16 chunks of BK=32), double
// buffered; phase 2 from padded LDS h-tile. grid (256, 3).
// (unchanged from round 8 -- see its journal entry)
// ---------------------------------------------------------------------------
#define MLP_BUF 20480
__global__ __launch_bounds__(256, 3) void mlp_kernel(
    const float* __restrict__ x0, const float* __restrict__ x1,
    const float* __restrict__ x2,
    const ushort_t* __restrict__ w1t3,
    const float* __restrict__ b1_0, const float* __restrict__ b1_1,
    const float* __restrict__ b1_2,
    const ushort_t* __restrict__ w2t3,
    const float* __restrict__ b2_0, const float* __restrict__ b2_1,
    const float* __restrict__ b2_2,
    float* __restrict__ y3,
    float* __restrict__ colsum, float* __restrict__ colsumsq)
{
  const int z = blockIdx.y;
  const float* X  = z == 0 ? x0 : (z == 1 ? x1 : x2);
  const float* B1 = z == 0 ? b1_0 : (z == 1 ? b1_1 : b1_2);
  const float* B2 = z == 0 ? b2_0 : (z == 1 ? b2_1 : b2_2);
  const ushort_t* W1t = w1t3 + (size_t)z * DHID * DIN;
  const ushort_t* W2t = w2t3 + (size_t)z * DOUT * DHID;
  float* Y    = y3 + (size_t)z * NROWS * DOUT;
  float* csum = colsum + z * DOUT;
  float* csq  = colsumsq + z * DOUT;

  __shared__ __align__(16) char lds[2 * MLP_BUF];
  ushort_t* hs = (ushort_t*)lds;  // [32][264] overlays buf0

  const int tid = threadIdx.x, lane = tid & 63, wave = tid >> 6;
  const int quad = lane >> 4, l16 = lane & 15;
  const int m0 = blockIdx.x * 32;

  const char* w1b = (const char*)W1t;
  const char* wsrc[4];
#pragma unroll
  for (int jj = 0; jj < 4; jj++)
    wsrc[jj] = w1b + (size_t)(16 * (wave * 4 + jj) + l16) * 1024 +
               (lane >> 4) * 16;
  const int row8 = lane >> 3, slot = lane & 7;
  const int gseg = (slot + row8) & 7;
  const char* xsrc = (const char*)X +
      (size_t)(m0 + 8 * wave + row8) * 2048 + gseg * 16;

  f32x4 acc1[2][4] = {};
#pragma unroll
  for (int jj = 0; jj < 4; jj++)
    dma16(wsrc[jj], lds + (wave * 4 + jj) * 1024);
  dma16(xsrc, lds + 16384 + wave * 1024);
  __syncthreads();

  for (int c = 0; c < 16; c++) {
    const int buf = c & 1;
    if (c + 1 < 16) {
      char* dst = lds + (buf ^ 1) * MLP_BUF;
#pragma unroll
      for (int jj = 0; jj < 4; jj++)
        dma16(wsrc[jj] + (c + 1) * 64, dst + (wave * 4 + jj) * 1024);
      dma16(xsrc + (c + 1) * 128, dst + 16384 + wave * 1024);
    }
    const char* wb = lds + buf * MLP_BUF;
    const char* xb = wb + 16384;
    bf16x8 a[2];
#pragma unroll
    for (int mt = 0; mt < 2; mt++) {
      const int r = mt * 16 + l16, r7 = r & 7;
      const int s0 = (2 * quad - r7) & 7, s1 = (2 * quad + 1 - r7) & 7;
      float4 v0 = *(const float4*)(xb + r * 128 + s0 * 16);
      float4 v1 = *(const float4*)(xb + r * 128 + s1 * 16);
      a[mt] = cvt8(v0, v1);
    }
    bf16x8 b[4];
#pragma unroll
    for (int ct = 0; ct < 4; ct++)
      b[ct] = *(const bf16x8*)(wb + (wave * 4 + ct) * 1024 + quad * 256 +
                               l16 * 16);
#pragma unroll
    for (int mt = 0; mt < 2; mt++)
#pragma unroll
      for (int ct = 0; ct < 4; ct++)
        acc1[mt][ct] = __builtin_amdgcn_mfma_f32_16x16x32_bf16(
            a[mt], b[ct], acc1[mt][ct], 0, 0, 0);
    __syncthreads();
  }

  bf16x8 b2f[2][8];
#pragma unroll
  for (int ct = 0; ct < 2; ct++)
#pragma unroll
    for (int kk = 0; kk < 8; kk++)
      b2f[ct][kk] = *(const bf16x8*)(W2t +
          (size_t)(wave * 32 + ct * 16 + l16) * DHID + kk * 32 + quad * 8);

#pragma unroll
  for (int ct = 0; ct < 4; ct++) {
    float bb = B1[wave * 64 + ct * 16 + l16];
#pragma unroll
    for (int mt = 0; mt < 2; mt++)
#pragma unroll
      for (int reg = 0; reg < 4; reg++) {
        float v = fmaxf(acc1[mt][ct][reg] + bb, 0.0f);
        hs[(mt * 16 + quad * 4 + reg) * 264 + wave * 64 + ct * 16 + l16] =
            (ushort_t)f2bf(v);
      }
  }
  __syncthreads();

  f32x4 acc2[2][2] = {};
#pragma unroll
  for (int kk = 0; kk < 8; kk++) {
    bf16x8 a2[2];
#pragma unroll
    for (int mt = 0; mt < 2; mt++)
      a2[mt] = *(const bf16x8*)(hs + (mt * 16 + l16) * 264 + kk * 32 +
                                quad * 8);
#pragma unroll
    for (int mt = 0; mt < 2; mt++)
#pragma unroll
      for (int ct = 0; ct < 2; ct++)
        acc2[mt][ct] = __builtin_amdgcn_mfma_f32_16x16x32_bf16(
            a2[mt], b2f[ct][kk], acc2[mt][ct], 0, 0, 0);
  }

#pragma unroll
  for (int ct = 0; ct < 2; ct++) {
    const int colo = wave * 32 + ct * 16 + l16;
    float bb = B2[colo];
    float cs = 0.0f, cq = 0.0f;
#pragma unroll
    for (int mt = 0; mt < 2; mt++)
#pragma unroll
      for (int reg = 0; reg < 4; reg++) {
        float v = acc2[mt][ct][reg] + bb;
        Y[(size_t)(m0 + mt * 16 + quad * 4 + reg) * DOUT + colo] = v;
        cs += v; cq += v * v;
      }
    cs += __shfl_xor(cs, 16, 64); cs += __shfl_xor(cs, 32, 64);
    cq += __shfl_xor(cq, 16, 64); cq += __shfl_xor(cq, 32, 64);
    if (lane < 16) {
      atomicAdd(&csum[colo], cs);
      atomicAdd(&csq[colo], cq);
    }
  }
}

// ---------------------------------------------------------------------------
// Whiten v9: wave-per-row, zero barriers, stats folded in. Each lane owns
// cols (lane, lane+64) of its row; mu/invsd recomputed inline from
// colsum/colsumsq (~12 VALU, L1-resident); norms & pos via 6-step
// xor-shuffles. Block = 4 waves = 4 rows. grid 2048.
// ---------------------------------------------------------------------------
__global__ __launch_bounds__(256) void whiten_kernel(
    const float* __restrict__ y3,
    const float* __restrict__ colsum, const float* __restrict__ colsumsq,
    ushort_t* __restrict__ zB, ushort_t* __restrict__ zE,
    ushort_t* __restrict__ zF,
    ushort_t* __restrict__ zBs, ushort_t* __restrict__ zEs,
    float* __restrict__ pos)
{
  const int tid = threadIdx.x, lane = tid & 63, wave = tid >> 6;
  const int row = blockIdx.x * 4 + wave;
  const size_t base = (size_t)row * DOUT;
  const size_t hsz = (size_t)NROWS * DOUT;
  const int c0 = lane, c1 = lane + 64;

  float mu[3][2], isd[3][2];
#pragma unroll
  for (int h = 0; h < 3; h++) {
#pragma unroll
    for (int cc = 0; cc < 2; cc++) {
      const int idx = h * DOUT + (cc ? c1 : c0);
      float m = colsum[idx] * (1.0f / NROWS);
      float var = (colsumsq[idx] - (float)NROWS * m * m) *
                  (1.0f / (NROWS - 1));
      mu[h][cc] = m;
      isd[h][cc] = 1.0f / (sqrtf(fmaxf(var, 0.0f)) + 1e-5f);
    }
  }

  float vB0 = (y3[base + c0]           - mu[0][0]) * isd[0][0];
  float vB1 = (y3[base + c1]           - mu[0][1]) * isd[0][1];
  float vE0 = (y3[base + hsz + c0]     - mu[1][0]) * isd[1][0];
  float vE1 = (y3[base + hsz + c1]     - mu[1][1]) * isd[1][1];
  float vF0 = (y3[base + 2 * hsz + c0] - mu[2][0]) * isd[2][0];
  float vF1 = (y3[base + 2 * hsz + c1] - mu[2][1]) * isd[2][1];

  float nB = vB0 * vB0 + vB1 * vB1;
  float nE = vE0 * vE0 + vE1 * vE1;
  float nF = vF0 * vF0 + vF1 * vF1;
#pragma unroll
  for (int o = 1; o < 64; o <<= 1) {
    nB += __shfl_xor(nB, o, 64);
    nE += __shfl_xor(nE, o, 64);
    nF += __shfl_xor(nF, o, 64);
  }
  float iB = 1.0f / fmaxf(sqrtf(nB), 1e-12f);
  float iE = 1.0f / fmaxf(sqrtf(nE), 1e-12f);
  float iF = 1.0f / fmaxf(sqrtf(nF), 1e-12f);
  float zb0 = vB0 * iB, zb1 = vB1 * iB;
  float ze0 = vE0 * iE, ze1 = vE1 * iE;
  float zf0 = vF0 * iF, zf1 = vF1 * iF;

  zB[base + c0]  = (ushort_t)f2bf(zb0);
  zB[base + c1]  = (ushort_t)f2bf(zb1);
  zE[base + c0]  = (ushort_t)f2bf(ze0);
  zE[base + c1]  = (ushort_t)f2bf(ze1);
  zF[base + c0]  = (ushort_t)f2bf(zf0);
  zF[base + c1]  = (ushort_t)f2bf(zf1);
  zBs[base + c0] = (ushort_t)f2bf(zb0 * LOG2E);
  zBs[base + c1] = (ushort_t)f2bf(zb1 * LOG2E);
  zEs[base + c0] = (ushort_t)f2bf(ze0 * LOG2E);
  zEs[base + c1] = (ushort_t)f2bf(ze1 * LOG2E);

  float pBE = zb0 * ze0 + zb1 * ze1;
  float pBF = zb0 * zf0 + zb1 * zf1;
  float pEF = ze0 * zf0 + ze1 * zf1;
#pragma unroll
  for (int o = 1; o < 64; o <<= 1) {
    pBE += __shfl_xor(pBE, o, 64);
    pBF += __shfl_xor(pBF, o, 64);
    pEF += __shfl_xor(pEF, o, 64);
  }
  if (lane == 0) {
    pos[row]             = pBE;
    pos[NROWS + row]     = pBF;
    pos[2 * NROWS + row] = pEF;
  }
}

// ---------------------------------------------------------------------------
// Gram v9: rowsum_i += sum_j exp2(Us_i . V_j), 5 combos. Async LDS staging;
// chunk = 64 cols per barrier, processed as two 32-col stages (b/acc regs
// reused per stage -> register count unchanged; stage-A exp2 overlaps
// stage-B MFMA). LDS 2 x 16 KB. G_NCH=16 chunks (1024 cols).
// grid (32, 8, 5) = 1280 blocks = exactly 5/CU residency.
// ---------------------------------------------------------------------------
#define G_NCH 16                    // 64-col chunks per block
__global__ __launch_bounds__(256, 3) void gram_kernel(
    const ushort_t* __restrict__ zB, const ushort_t* __restrict__ zE,
    const ushort_t* __restrict__ zF,
    const ushort_t* __restrict__ zBs, const ushort_t* __restrict__ zEs,
    float* __restrict__ rowsum)
{
  const ushort_t *U, *V;
  float* rs;
  switch (blockIdx.z) {
    case 0:  U = zBs; V = zB; rs = rowsum;             break;
    case 1:  U = zEs; V = zE; rs = rowsum + NROWS;     break;
    case 2:  U = zBs; V = zE; rs = rowsum + 2 * NROWS; break;
    case 3:  U = zBs; V = zF; rs = rowsum + 3 * NROWS; break;
    default: U = zEs; V = zF; rs = rowsum + 4 * NROWS; break;
  }

  const int tid = threadIdx.x, lane = tid & 63, wave = tid >> 6;
  const int quad = lane >> 4, l16 = lane & 15;
  const int m0 = blockIdx.x * 256 + wave * 64;      // waves stacked in m
  const int col0 = blockIdx.y * (64 * G_NCH);

  __shared__ __align__(16) ushort_t sbuf[2][8192];  // 2 x 16 KB

  // cache this wave's A fragments: 64 rows x 128 k (16 frags = 64 regs)
  const ushort_t* ua = U + (size_t)(m0 + l16) * DOUT + quad * 8;
  bf16x8 a[4][4];
#pragma unroll
  for (int rt = 0; rt < 4; rt++)
#pragma unroll
    for (int ki = 0; ki < 4; ki++)
      a[rt][ki] = *(const bf16x8*)(ua + rt * 16 * DOUT + ki * 32);

  // DMA: per chunk, 4 insts/wave: halves h=0,1 (cols +0/+32), insts j=2w,
  // 2w+1 per half; lane i -> col i&31, k-seg s = 4w + 2*(j&1)... as r8.
  const char* Vb = (const char*)V;
  const int r_ = lane & 31, hi_ = lane >> 5;
  const int s0 = 4 * wave + hi_, s1 = 4 * wave + 2 + hi_;
  const char* g0 = Vb + (size_t)(col0 + r_) * 256 + s0 * 16;
  const char* g1 = Vb + (size_t)(col0 + r_) * 256 + s1 * 16;

  float rsum[4][4] = {};
  const f32x4 zero = {0.0f, 0.0f, 0.0f, 0.0f};

  // prime chunk 0 (both halves)
  dma16(g0, &sbuf[0][(2 * wave) * 512]);
  dma16(g1, &sbuf[0][(2 * wave + 1) * 512]);
  dma16(g0 + 8192, &sbuf[0][4096 + (2 * wave) * 512]);
  dma16(g1 + 8192, &sbuf[0][4096 + (2 * wave + 1) * 512]);
  __syncthreads();

  for (int c = 0; c < G_NCH; c++) {
    const int buf = c & 1;
    if (c + 1 < G_NCH) {
      const size_t go = (size_t)(c + 1) * 16384;
      dma16(g0 + go, &sbuf[buf ^ 1][(2 * wave) * 512]);
      dma16(g1 + go, &sbuf[buf ^ 1][(2 * wave + 1) * 512]);
      dma16(g0 + go + 8192, &sbuf[buf ^ 1][4096 + (2 * wave) * 512]);
      dma16(g1 + go + 8192, &sbuf[buf ^ 1][4096 + (2 * wave + 1) * 512]);
    }
#pragma unroll
    for (int h = 0; h < 2; h++) {
      const char* sb = (const char*)&sbuf[buf][h * 4096];
      bf16x8 b[4][2];
#pragma unroll
      for (int ki = 0; ki < 4; ki++)
#pragma unroll
        for (int ct = 0; ct < 2; ct++)
          b[ki][ct] = *(const bf16x8*)(sb + (ki * 4 + quad) * 512 +
                                       (ct * 16 + l16) * 16);
      f32x4 acc[4][2];
#pragma unroll
      for (int ki = 0; ki < 4; ki++)
#pragma unroll
        for (int rt = 0; rt < 4; rt++)
#pragma unroll
          for (int ct = 0; ct < 2; ct++)
            acc[rt][ct] = __builtin_amdgcn_mfma_f32_16x16x32_bf16(
                a[rt][ki], b[ki][ct], ki == 0 ? zero : acc[rt][ct], 0, 0, 0);
#pragma unroll
      for (int rt = 0; rt < 4; rt++)
#pragma unroll
        for (int reg = 0; reg < 4; reg++)
          rsum[rt][reg] += FAST_EXP2(acc[rt][0][reg]) +
                           FAST_EXP2(acc[rt][1][reg]);
    }
    __syncthreads();
  }

  // one cross-lane reduction over l16 + one atomic per row per block
#pragma unroll
  for (int rt = 0; rt < 4; rt++)
#pragma unroll
    for (int reg = 0; reg < 4; reg++) {
      float s = rsum[rt][reg];
      s += __shfl_xor(s, 1, 64);
      s += __shfl_xor(s, 2, 64);
      s += __shfl_xor(s, 4, 64);
      s += __shfl_xor(s, 8, 64);
      if (l16 == 0)
        atomicAdd(&rs[m0 + rt * 16 + quad * 4 + reg], s);
    }
}

// ---------------------------------------------------------------------------
// Final loss. logits[i,i] masked to 0: self + (1 - e).
// ---------------------------------------------------------------------------
__global__ __launch_bounds__(1024) void loss_kernel(
    const float* __restrict__ rowsum, const float* __restrict__ pos,
    float* __restrict__ out)
{
  const float* sB  = rowsum;
  const float* sE  = rowsum + NROWS;
  const float* cBE = rowsum + 2 * NROWS;
  const float* cBF = rowsum + 3 * NROWS;
  const float* cEF = rowsum + 4 * NROWS;
  const float* pBE = pos;
  const float* pBF = pos + NROWS;
  const float* pEF = pos + 2 * NROWS;

  const float corr = 1.0f - expf(1.0f);
  float local = 0.0f;
  for (int i = threadIdx.x; i < NROWS; i += 1024) {
    float selB = sB[i] + corr;
    float selE = sE[i] + corr;
    local += __logf(selB + cBE[i]) - pBE[i];
    local += __logf(selB + cBF[i]) - pBF[i];
    local += __logf(selE + cEF[i]) - pEF[i];
  }
  __shared__ float red[16];
#pragma unroll
  for (int o = 32; o > 0; o >>= 1) local += __shfl_down(local, o, 64);
  int lane = threadIdx.x & 63, wv = threadIdx.x >> 6;
  if (lane == 0) red[wv] = local;
  __syncthreads();
  if (threadIdx.x == 0) {
    float t = 0.0f;
#pragma unroll
    for (int w = 0; w < 16; w++) t += red[w];
    out[0] = t / (3.0f * (float)NROWS);
  }
}

// ---------------------------------------------------------------------------
extern "C" void kernel_launch(void* const* d_in, const int* in_sizes, int n_in,
                              void* d_out, int out_size, void* d_ws, size_t ws_size,
                              hipStream_t stream)
{
  const float* xs[3] = {(const float*)d_in[0], (const float*)d_in[1], (const float*)d_in[2]};
  const float* W1[3] = {(const float*)d_in[3], (const float*)d_in[7],  (const float*)d_in[11]};
  const float* b1[3] = {(const float*)d_in[4], (const float*)d_in[8],  (const float*)d_in[12]};
  const float* W2[3] = {(const float*)d_in[5], (const float*)d_in[9],  (const float*)d_in[13]};
  const float* b2[3] = {(const float*)d_in[6], (const float*)d_in[10], (const float*)d_in[14]};

  float* ws = (float*)d_ws;
  // workspace layout (float offsets):
  float* colsum   = ws;            // 384   [zeroed by prep_w]
  float* colsumsq = ws + 384;      // 384   [zeroed by prep_w]
  float* rowsum   = ws + 768;      // 5*8192 [zeroed by prep_w]
  float* pos      = ws + 42496;    // 3*8192 -> ends 67072
  ushort_t* w1t3 = (ushort_t*)(ws + 67072);    // 3*256*512 bf16 = 196608 fl
  ushort_t* w2t3 = (ushort_t*)(ws + 263680);   // 3*128*256 bf16 = 49152 fl
  float*    y3   = ws + 312832;                // 3*8192*128 fp32 = 3145728 fl
  ushort_t* zB   = (ushort_t*)(ws + 3458560);  // 5 x 8192*128 bf16
  ushort_t* zE   = zB  + (size_t)NROWS * DOUT;
  ushort_t* zF   = zE  + (size_t)NROWS * DOUT;
  ushort_t* zBs  = zF  + (size_t)NROWS * DOUT;
  ushort_t* zEs  = zBs + (size_t)NROWS * DOUT;
  // peak ws usage: 6,080,000 floats = 24.3 MB

  prep_w_kernel<<<dim3(640, 3), 256, 0, stream>>>(
      W1[0], W1[1], W1[2], W2[0], W2[1], W2[2], w1t3, w2t3, ws);
  mlp_kernel<<<dim3(256, 3), 256, 0, stream>>>(
      xs[0], xs[1], xs[2], w1t3, b1[0], b1[1], b1[2],
      w2t3, b2[0], b2[1], b2[2], y3, colsum, colsumsq);
  whiten_kernel<<<2048, 256, 0, stream>>>(
      y3, colsum, colsumsq, zB, zE, zF, zBs, zEs, pos);
  gram_kernel<<<dim3(32, 8, 5), 256, 0, stream>>>(zB, zE, zF, zBs, zEs, rowsum);
  loss_kernel<<<1, 1024, 0, stream>>>(rowsum, pos, (float*)d_out);
}

// Round 10
// 233.401 us; speedup vs baseline: 1.1433x; 1.1433x over previous
//
#include <hip/hip_runtime.h>
#include <hip/hip_bf16.h>
#include <math.h>

#define NROWS 8192
#define DIN   512
#define DHID  256
#define DOUT  128
#define LOG2E 1.4426950408889634f

typedef unsigned short ushort_t;
typedef __attribute__((ext_vector_type(8))) short bf16x8;
typedef __attribute__((ext_vector_type(4))) float f32x4;

#if defined(__has_builtin)
#  if __has_builtin(__builtin_amdgcn_exp2f)
#    define FAST_EXP2(x) __builtin_amdgcn_exp2f(x)
#  else
#    define FAST_EXP2(x) exp2f(x)
#  endif
#else
#  define FAST_EXP2(x) exp2f(x)
#endif

__device__ __forceinline__ short f2bf(float x) {
  __hip_bfloat16 h = __float2bfloat16(x);
  return *(short*)&h;
}

__device__ __forceinline__ bf16x8 cvt8(float4 lo, float4 hi) {
  bf16x8 r;
  r[0] = f2bf(lo.x); r[1] = f2bf(lo.y); r[2] = f2bf(lo.z); r[3] = f2bf(lo.w);
  r[4] = f2bf(hi.x); r[5] = f2bf(hi.y); r[6] = f2bf(hi.z); r[7] = f2bf(hi.w);
  return r;
}

// async 16B global->LDS copy: lds dest = wave-uniform base + lane*16.
__device__ __forceinline__ void dma16(const void* g, void* l) {
  __builtin_amdgcn_global_load_lds(
      (const __attribute__((address_space(1))) unsigned int*)g,
      (__attribute__((address_space(3))) unsigned int*)l, 16, 0, 0);
}

// ---------------------------------------------------------------------------
// Weight prep (all 3 heads) + workspace zeroing (replaces hipMemsetAsync).
// W1 (512x256)->w1t (256x512), W2 (256x128)->w2t (128x256), fp32 -> bf16,
// transposed so k is contiguous. grid (640, 3). z==0, bx<163 blocks also
// zero the 41728-float accumulator region (163*256 == 41728 exactly).
// ---------------------------------------------------------------------------
__global__ __launch_bounds__(256) void prep_w_kernel(
    const float* __restrict__ W1_0, const float* __restrict__ W1_1,
    const float* __restrict__ W1_2,
    const float* __restrict__ W2_0, const float* __restrict__ W2_1,
    const float* __restrict__ W2_2,
    ushort_t* __restrict__ w1t3, ushort_t* __restrict__ w2t3,
    float* __restrict__ zero_region)
{
  const int z = blockIdx.y;
  if (z == 0 && blockIdx.x < 163)
    zero_region[blockIdx.x * 256 + threadIdx.x] = 0.0f;
  const float* W1 = z == 0 ? W1_0 : (z == 1 ? W1_1 : W1_2);
  const float* W2 = z == 0 ? W2_0 : (z == 1 ? W2_1 : W2_2);
  int idx = blockIdx.x * 256 + threadIdx.x;
  if (idx < DHID * DIN) {
    int n = idx >> 9, k = idx & (DIN - 1);
    w1t3[(size_t)z * DHID * DIN + idx] = f2bf(W1[(size_t)k * DHID + n]);
  } else {
    int j = idx - DHID * DIN;
    int n = j >> 8, k = j & (DHID - 1);
    w2t3[(size_t)z * DOUT * DHID + j] = f2bf(W2[(size_t)k * DOUT + n]);
  }
}

// ---------------------------------------------------------------------------
// Fused MLP (all heads): y = (relu(x@W1+b1))@W2 + b2, fp32 + col stats.
// Block = 32 rows; phase 1 = DMA-staged K-loop (16 chunks of BK=32), double
// buffered; phase 2 from padded LDS h-tile. grid (256, 3).
// ---------------------------------------------------------------------------
#define MLP_BUF 20480
__global__ __launch_bounds__(256, 3) void mlp_kernel(
    const float* __restrict__ x0, const float* __restrict__ x1,
    const float* __restrict__ x2,
    const ushort_t* __restrict__ w1t3,
    const float* __restrict__ b1_0, const float* __restrict__ b1_1,
    const float* __restrict__ b1_2,
    const ushort_t* __restrict__ w2t3,
    const float* __restrict__ b2_0, const float* __restrict__ b2_1,
    const float* __restrict__ b2_2,
    float* __restrict__ y3,
    float* __restrict__ colsum, float* __restrict__ colsumsq)
{
  const int z = blockIdx.y;
  const float* X  = z == 0 ? x0 : (z == 1 ? x1 : x2);
  const float* B1 = z == 0 ? b1_0 : (z == 1 ? b1_1 : b1_2);
  const float* B2 = z == 0 ? b2_0 : (z == 1 ? b2_1 : b2_2);
  const ushort_t* W1t = w1t3 + (size_t)z * DHID * DIN;
  const ushort_t* W2t = w2t3 + (size_t)z * DOUT * DHID;
  float* Y    = y3 + (size_t)z * NROWS * DOUT;
  float* csum = colsum + z * DOUT;
  float* csq  = colsumsq + z * DOUT;

  __shared__ __align__(16) char lds[2 * MLP_BUF];
  ushort_t* hs = (ushort_t*)lds;  // [32][264] overlays buf0

  const int tid = threadIdx.x, lane = tid & 63, wave = tid >> 6;
  const int quad = lane >> 4, l16 = lane & 15;
  const int m0 = blockIdx.x * 32;

  const char* w1b = (const char*)W1t;
  const char* wsrc[4];
#pragma unroll
  for (int jj = 0; jj < 4; jj++)
    wsrc[jj] = w1b + (size_t)(16 * (wave * 4 + jj) + l16) * 1024 +
               (lane >> 4) * 16;
  const int row8 = lane >> 3, slot = lane & 7;
  const int gseg = (slot + row8) & 7;
  const char* xsrc = (const char*)X +
      (size_t)(m0 + 8 * wave + row8) * 2048 + gseg * 16;

  f32x4 acc1[2][4] = {};
#pragma unroll
  for (int jj = 0; jj < 4; jj++)
    dma16(wsrc[jj], lds + (wave * 4 + jj) * 1024);
  dma16(xsrc, lds + 16384 + wave * 1024);
  __syncthreads();

  for (int c = 0; c < 16; c++) {
    const int buf = c & 1;
    if (c + 1 < 16) {
      char* dst = lds + (buf ^ 1) * MLP_BUF;
#pragma unroll
      for (int jj = 0; jj < 4; jj++)
        dma16(wsrc[jj] + (c + 1) * 64, dst + (wave * 4 + jj) * 1024);
      dma16(xsrc + (c + 1) * 128, dst + 16384 + wave * 1024);
    }
    const char* wb = lds + buf * MLP_BUF;
    const char* xb = wb + 16384;
    bf16x8 a[2];
#pragma unroll
    for (int mt = 0; mt < 2; mt++) {
      const int r = mt * 16 + l16, r7 = r & 7;
      const int s0 = (2 * quad - r7) & 7, s1 = (2 * quad + 1 - r7) & 7;
      float4 v0 = *(const float4*)(xb + r * 128 + s0 * 16);
      float4 v1 = *(const float4*)(xb + r * 128 + s1 * 16);
      a[mt] = cvt8(v0, v1);
    }
    bf16x8 b[4];
#pragma unroll
    for (int ct = 0; ct < 4; ct++)
      b[ct] = *(const bf16x8*)(wb + (wave * 4 + ct) * 1024 + quad * 256 +
                               l16 * 16);
#pragma unroll
    for (int mt = 0; mt < 2; mt++)
#pragma unroll
      for (int ct = 0; ct < 4; ct++)
        acc1[mt][ct] = __builtin_amdgcn_mfma_f32_16x16x32_bf16(
            a[mt], b[ct], acc1[mt][ct], 0, 0, 0);
    __syncthreads();
  }

  bf16x8 b2f[2][8];
#pragma unroll
  for (int ct = 0; ct < 2; ct++)
#pragma unroll
    for (int kk = 0; kk < 8; kk++)
      b2f[ct][kk] = *(const bf16x8*)(W2t +
          (size_t)(wave * 32 + ct * 16 + l16) * DHID + kk * 32 + quad * 8);

#pragma unroll
  for (int ct = 0; ct < 4; ct++) {
    float bb = B1[wave * 64 + ct * 16 + l16];
#pragma unroll
    for (int mt = 0; mt < 2; mt++)
#pragma unroll
      for (int reg = 0; reg < 4; reg++) {
        float v = fmaxf(acc1[mt][ct][reg] + bb, 0.0f);
        hs[(mt * 16 + quad * 4 + reg) * 264 + wave * 64 + ct * 16 + l16] =
            (ushort_t)f2bf(v);
      }
  }
  __syncthreads();

  f32x4 acc2[2][2] = {};
#pragma unroll
  for (int kk = 0; kk < 8; kk++) {
    bf16x8 a2[2];
#pragma unroll
    for (int mt = 0; mt < 2; mt++)
      a2[mt] = *(const bf16x8*)(hs + (mt * 16 + l16) * 264 + kk * 32 +
                                quad * 8);
#pragma unroll
    for (int mt = 0; mt < 2; mt++)
#pragma unroll
      for (int ct = 0; ct < 2; ct++)
        acc2[mt][ct] = __builtin_amdgcn_mfma_f32_16x16x32_bf16(
            a2[mt], b2f[ct][kk], acc2[mt][ct], 0, 0, 0);
  }

#pragma unroll
  for (int ct = 0; ct < 2; ct++) {
    const int colo = wave * 32 + ct * 16 + l16;
    float bb = B2[colo];
    float cs = 0.0f, cq = 0.0f;
#pragma unroll
    for (int mt = 0; mt < 2; mt++)
#pragma unroll
      for (int reg = 0; reg < 4; reg++) {
        float v = acc2[mt][ct][reg] + bb;
        Y[(size_t)(m0 + mt * 16 + quad * 4 + reg) * DOUT + colo] = v;
        cs += v; cq += v * v;
      }
    cs += __shfl_xor(cs, 16, 64); cs += __shfl_xor(cs, 32, 64);
    cq += __shfl_xor(cq, 16, 64); cq += __shfl_xor(cq, 32, 64);
    if (lane < 16) {
      atomicAdd(&csum[colo], cs);
      atomicAdd(&csq[colo], cq);
    }
  }
}

// ---------------------------------------------------------------------------
// Whiten v9: wave-per-row, zero barriers, stats folded in. Each lane owns
// cols (lane, lane+64) of its row; mu/invsd recomputed inline from
// colsum/colsumsq; norms & pos via 6-step xor-shuffles. grid 2048.
// ---------------------------------------------------------------------------
__global__ __launch_bounds__(256) void whiten_kernel(
    const float* __restrict__ y3,
    const float* __restrict__ colsum, const float* __restrict__ colsumsq,
    ushort_t* __restrict__ zB, ushort_t* __restrict__ zE,
    ushort_t* __restrict__ zF,
    ushort_t* __restrict__ zBs, ushort_t* __restrict__ zEs,
    float* __restrict__ pos)
{
  const int tid = threadIdx.x, lane = tid & 63, wave = tid >> 6;
  const int row = blockIdx.x * 4 + wave;
  const size_t base = (size_t)row * DOUT;
  const size_t hsz = (size_t)NROWS * DOUT;
  const int c0 = lane, c1 = lane + 64;

  float mu[3][2], isd[3][2];
#pragma unroll
  for (int h = 0; h < 3; h++) {
#pragma unroll
    for (int cc = 0; cc < 2; cc++) {
      const int idx = h * DOUT + (cc ? c1 : c0);
      float m = colsum[idx] * (1.0f / NROWS);
      float var = (colsumsq[idx] - (float)NROWS * m * m) *
                  (1.0f / (NROWS - 1));
      mu[h][cc] = m;
      isd[h][cc] = 1.0f / (sqrtf(fmaxf(var, 0.0f)) + 1e-5f);
    }
  }

  float vB0 = (y3[base + c0]           - mu[0][0]) * isd[0][0];
  float vB1 = (y3[base + c1]           - mu[0][1]) * isd[0][1];
  float vE0 = (y3[base + hsz + c0]     - mu[1][0]) * isd[1][0];
  float vE1 = (y3[base + hsz + c1]     - mu[1][1]) * isd[1][1];
  float vF0 = (y3[base + 2 * hsz + c0] - mu[2][0]) * isd[2][0];
  float vF1 = (y3[base + 2 * hsz + c1] - mu[2][1]) * isd[2][1];

  float nB = vB0 * vB0 + vB1 * vB1;
  float nE = vE0 * vE0 + vE1 * vE1;
  float nF = vF0 * vF0 + vF1 * vF1;
#pragma unroll
  for (int o = 1; o < 64; o <<= 1) {
    nB += __shfl_xor(nB, o, 64);
    nE += __shfl_xor(nE, o, 64);
    nF += __shfl_xor(nF, o, 64);
  }
  float iB = 1.0f / fmaxf(sqrtf(nB), 1e-12f);
  float iE = 1.0f / fmaxf(sqrtf(nE), 1e-12f);
  float iF = 1.0f / fmaxf(sqrtf(nF), 1e-12f);
  float zb0 = vB0 * iB, zb1 = vB1 * iB;
  float ze0 = vE0 * iE, ze1 = vE1 * iE;
  float zf0 = vF0 * iF, zf1 = vF1 * iF;

  zB[base + c0]  = (ushort_t)f2bf(zb0);
  zB[base + c1]  = (ushort_t)f2bf(zb1);
  zE[base + c0]  = (ushort_t)f2bf(ze0);
  zE[base + c1]  = (ushort_t)f2bf(ze1);
  zF[base + c0]  = (ushort_t)f2bf(zf0);
  zF[base + c1]  = (ushort_t)f2bf(zf1);
  zBs[base + c0] = (ushort_t)f2bf(zb0 * LOG2E);
  zBs[base + c1] = (ushort_t)f2bf(zb1 * LOG2E);
  zEs[base + c0] = (ushort_t)f2bf(ze0 * LOG2E);
  zEs[base + c1] = (ushort_t)f2bf(ze1 * LOG2E);

  float pBE = zb0 * ze0 + zb1 * ze1;
  float pBF = zb0 * zf0 + zb1 * zf1;
  float pEF = ze0 * zf0 + ze1 * zf1;
#pragma unroll
  for (int o = 1; o < 64; o <<= 1) {
    pBE += __shfl_xor(pBE, o, 64);
    pBF += __shfl_xor(pBF, o, 64);
    pEF += __shfl_xor(pEF, o, 64);
  }
  if (lane == 0) {
    pos[row]             = pBE;
    pos[NROWS + row]     = pBF;
    pos[2 * NROWS + row] = pEF;
  }
}

// ---------------------------------------------------------------------------
// Gram (round-8 known-good): rowsum_i += sum_j exp2(Us_i . V_j), 5 combos.
// Async LDS staging, 32-col chunks, G_NCH=32, grid (32, 8, 5) = 1280 blocks.
// NOTE: do NOT widen the per-barrier stage: >1 stage unrolled doubles live
// b/acc registers past ~150 and spills to scratch (round-9 regression:
// WRITE_SIZE 5 -> 41 MB).
// ---------------------------------------------------------------------------
#define G_CH  32                    // cols per chunk
#define G_NCH 32                    // chunks per block (1024 cols)
__global__ __launch_bounds__(256, 3) void gram_kernel(
    const ushort_t* __restrict__ zB, const ushort_t* __restrict__ zE,
    const ushort_t* __restrict__ zF,
    const ushort_t* __restrict__ zBs, const ushort_t* __restrict__ zEs,
    float* __restrict__ rowsum)
{
  const ushort_t *U, *V;
  float* rs;
  switch (blockIdx.z) {
    case 0:  U = zBs; V = zB; rs = rowsum;             break;
    case 1:  U = zEs; V = zE; rs = rowsum + NROWS;     break;
    case 2:  U = zBs; V = zE; rs = rowsum + 2 * NROWS; break;
    case 3:  U = zBs; V = zF; rs = rowsum + 3 * NROWS; break;
    default: U = zEs; V = zF; rs = rowsum + 4 * NROWS; break;
  }

  const int tid = threadIdx.x, lane = tid & 63, wave = tid >> 6;
  const int quad = lane >> 4, l16 = lane & 15;
  const int m0 = blockIdx.x * 256 + wave * 64;      // waves stacked in m
  const int col0 = blockIdx.y * (G_CH * G_NCH);

  __shared__ __align__(16) ushort_t sbuf[2][4096];  // 2 x 8 KB

  // cache this wave's A fragments: 64 rows x 128 k (16 frags = 64 VGPR)
  const ushort_t* ua = U + (size_t)(m0 + l16) * DOUT + quad * 8;
  bf16x8 a[4][4];
#pragma unroll
  for (int rt = 0; rt < 4; rt++)
#pragma unroll
    for (int ki = 0; ki < 4; ki++)
      a[rt][ki] = *(const bf16x8*)(ua + rt * 16 * DOUT + ki * 32);

  const char* Vb = (const char*)V;
  const int r_ = lane & 31, hi_ = lane >> 5;
  const int s0 = 4 * wave + hi_, s1 = 4 * wave + 2 + hi_;
  const char* g0 = Vb + (size_t)(col0 + r_) * 256 + (s0 >> 2) * 64 + (s0 & 3) * 16;
  const char* g1 = Vb + (size_t)(col0 + r_) * 256 + (s1 >> 2) * 64 + (s1 & 3) * 16;

  float rsum[4][4] = {};
  const f32x4 zero = {0.0f, 0.0f, 0.0f, 0.0f};

  // prime chunk 0
  dma16(g0, &sbuf[0][(2 * wave) * 512]);
  dma16(g1, &sbuf[0][(2 * wave + 1) * 512]);
  __syncthreads();

  for (int c = 0; c < G_NCH; c++) {
    const int buf = c & 1;
    if (c + 1 < G_NCH) {
      const size_t go = (size_t)(c + 1) * 8192;
      dma16(g0 + go, &sbuf[buf ^ 1][(2 * wave) * 512]);
      dma16(g1 + go, &sbuf[buf ^ 1][(2 * wave + 1) * 512]);
    }
    const char* sb = (const char*)&sbuf[buf][0];
    bf16x8 b[4][2];
#pragma unroll
    for (int ki = 0; ki < 4; ki++)
#pragma unroll
      for (int ct = 0; ct < 2; ct++)
        b[ki][ct] = *(const bf16x8*)(sb + (ki * 4 + quad) * 512 +
                                     (ct * 16 + l16) * 16);
    f32x4 acc[4][2];
#pragma unroll
    for (int ki = 0; ki < 4; ki++)
#pragma unroll
      for (int rt = 0; rt < 4; rt++)
#pragma unroll
        for (int ct = 0; ct < 2; ct++)
          acc[rt][ct] = __builtin_amdgcn_mfma_f32_16x16x32_bf16(
              a[rt][ki], b[ki][ct], ki == 0 ? zero : acc[rt][ct], 0, 0, 0);
#pragma unroll
    for (int rt = 0; rt < 4; rt++)
#pragma unroll
      for (int reg = 0; reg < 4; reg++)
        rsum[rt][reg] += FAST_EXP2(acc[rt][0][reg]) + FAST_EXP2(acc[rt][1][reg]);
    __syncthreads();
  }

#pragma unroll
  for (int rt = 0; rt < 4; rt++)
#pragma unroll
    for (int reg = 0; reg < 4; reg++) {
      float s = rsum[rt][reg];
      s += __shfl_xor(s, 1, 64);
      s += __shfl_xor(s, 2, 64);
      s += __shfl_xor(s, 4, 64);
      s += __shfl_xor(s, 8, 64);
      if (l16 == 0)
        atomicAdd(&rs[m0 + rt * 16 + quad * 4 + reg], s);
    }
}

// ---------------------------------------------------------------------------
// Final loss. logits[i,i] masked to 0: self + (1 - e).
// ---------------------------------------------------------------------------
__global__ __launch_bounds__(1024) void loss_kernel(
    const float* __restrict__ rowsum, const float* __restrict__ pos,
    float* __restrict__ out)
{
  const float* sB  = rowsum;
  const float* sE  = rowsum + NROWS;
  const float* cBE = rowsum + 2 * NROWS;
  const float* cBF = rowsum + 3 * NROWS;
  const float* cEF = rowsum + 4 * NROWS;
  const float* pBE = pos;
  const float* pBF = pos + NROWS;
  const float* pEF = pos + 2 * NROWS;

  const float corr = 1.0f - expf(1.0f);
  float local = 0.0f;
  for (int i = threadIdx.x; i < NROWS; i += 1024) {
    float selB = sB[i] + corr;
    float selE = sE[i] + corr;
    local += __logf(selB + cBE[i]) - pBE[i];
    local += __logf(selB + cBF[i]) - pBF[i];
    local += __logf(selE + cEF[i]) - pEF[i];
  }
  __shared__ float red[16];
#pragma unroll
  for (int o = 32; o > 0; o >>= 1) local += __shfl_down(local, o, 64);
  int lane = threadIdx.x & 63, wv = threadIdx.x >> 6;
  if (lane == 0) red[wv] = local;
  __syncthreads();
  if (threadIdx.x == 0) {
    float t = 0.0f;
#pragma unroll
    for (int w = 0; w < 16; w++) t += red[w];
    out[0] = t / (3.0f * (float)NROWS);
  }
}

// ---------------------------------------------------------------------------
extern "C" void kernel_launch(void* const* d_in, const int* in_sizes, int n_in,
                              void* d_out, int out_size, void* d_ws, size_t ws_size,
                              hipStream_t stream)
{
  const float* xs[3] = {(const float*)d_in[0], (const float*)d_in[1], (const float*)d_in[2]};
  const float* W1[3] = {(const float*)d_in[3], (const float*)d_in[7],  (const float*)d_in[11]};
  const float* b1[3] = {(const float*)d_in[4], (const float*)d_in[8],  (const float*)d_in[12]};
  const float* W2[3] = {(const float*)d_in[5], (const float*)d_in[9],  (const float*)d_in[13]};
  const float* b2[3] = {(const float*)d_in[6], (const float*)d_in[10], (const float*)d_in[14]};

  float* ws = (float*)d_ws;
  // workspace layout (float offsets):
  float* colsum   = ws;            // 384   [zeroed by prep_w]
  float* colsumsq = ws + 384;      // 384   [zeroed by prep_w]
  float* rowsum   = ws + 768;      // 5*8192 [zeroed by prep_w]
  float* pos      = ws + 42496;    // 3*8192 -> ends 67072
  ushort_t* w1t3 = (ushort_t*)(ws + 67072);    // 3*256*512 bf16 = 196608 fl
  ushort_t* w2t3 = (ushort_t*)(ws + 263680);   // 3*128*256 bf16 = 49152 fl
  float*    y3   = ws + 312832;                // 3*8192*128 fp32 = 3145728 fl
  ushort_t* zB   = (ushort_t*)(ws + 3458560);  // 5 x 8192*128 bf16
  ushort_t* zE   = zB  + (size_t)NROWS * DOUT;
  ushort_t* zF   = zE  + (size_t)NROWS * DOUT;
  ushort_t* zBs  = zF  + (size_t)NROWS * DOUT;
  ushort_t* zEs  = zBs + (size_t)NROWS * DOUT;
  // peak ws usage: 6,080,000 floats = 24.3 MB

  prep_w_kernel<<<dim3(640, 3), 256, 0, stream>>>(
      W1[0], W1[1], W1[2], W2[0], W2[1], W2[2], w1t3, w2t3, ws);
  mlp_kernel<<<dim3(256, 3), 256, 0, stream>>>(
      xs[0], xs[1], xs[2], w1t3, b1[0], b1[1], b1[2],
      w2t3, b2[0], b2[1], b2[2], y3, colsum, colsumsq);
  whiten_kernel<<<2048, 256, 0, stream>>>(
      y3, colsum, colsumsq, zB, zE, zF, zBs, zEs, pos);
  gram_kernel<<<dim3(32, 8, 5), 256, 0, stream>>>(zB, zE, zF, zBs, zEs, rowsum);
  loss_kernel<<<1, 1024, 0, stream>>>(rowsum, pos, (float*)d_out);
}

// Round 11
// 214.930 us; speedup vs baseline: 1.2416x; 1.0859x over previous
//
#include <hip/hip_runtime.h>
#include <hip/hip_bf16.h>
#include <math.h>

#define NROWS 8192
#define DIN   512
#define DHID  256
#define DOUT  128
#define LOG2E 1.4426950408889634f

typedef unsigned short ushort_t;
typedef __attribute__((ext_vector_type(8))) short bf16x8;
typedef __attribute__((ext_vector_type(4))) float f32x4;

#if defined(__has_builtin)
#  if __has_builtin(__builtin_amdgcn_exp2f)
#    define FAST_EXP2(x) __builtin_amdgcn_exp2f(x)
#  else
#    define FAST_EXP2(x) exp2f(x)
#  endif
#else
#  define FAST_EXP2(x) exp2f(x)
#endif

__device__ __forceinline__ short f2bf(float x) {
  __hip_bfloat16 h = __float2bfloat16(x);
  return *(short*)&h;
}

__device__ __forceinline__ float bf2f(ushort_t v) {
  unsigned int u = ((unsigned int)v) << 16;
  union { unsigned int u; float f; } c; c.u = u;
  return c.f;
}

__device__ __forceinline__ bf16x8 cvt8(float4 lo, float4 hi) {
  bf16x8 r;
  r[0] = f2bf(lo.x); r[1] = f2bf(lo.y); r[2] = f2bf(lo.z); r[3] = f2bf(lo.w);
  r[4] = f2bf(hi.x); r[5] = f2bf(hi.y); r[6] = f2bf(hi.z); r[7] = f2bf(hi.w);
  return r;
}

// async 16B global->LDS copy: lds dest = wave-uniform base + lane*16.
__device__ __forceinline__ void dma16(const void* g, void* l) {
  __builtin_amdgcn_global_load_lds(
      (const __attribute__((address_space(1))) unsigned int*)g,
      (__attribute__((address_space(3))) unsigned int*)l, 16, 0, 0);
}

// ---------------------------------------------------------------------------
// Weight prep v11: LDS-tiled coalesced transpose (64x64 tiles, pad 65),
// fp32 -> bf16. Also zeroes the ws accumulator region and d_out.
// grid (4, 12, 3): gy<8 -> W1 (512x256 -> 256x512); gy>=8 -> W2 (gx<2).
// ---------------------------------------------------------------------------
__global__ __launch_bounds__(256) void prep_w_kernel(
    const float* __restrict__ W1_0, const float* __restrict__ W1_1,
    const float* __restrict__ W1_2,
    const float* __restrict__ W2_0, const float* __restrict__ W2_1,
    const float* __restrict__ W2_2,
    ushort_t* __restrict__ w1t3, ushort_t* __restrict__ w2t3,
    float* __restrict__ zero_region, float* __restrict__ out)
{
  const int z = blockIdx.z, gx = blockIdx.x, gy = blockIdx.y;
  const int tid = threadIdx.x;
  if (z == 0) {
    int b = gy * 4 + gx;  // 48 blocks x 4 passes x 256 >= 41728
#pragma unroll
    for (int j = 0; j < 4; j++) {
      int idx = b * 256 + tid + j * 12288;
      if (idx < 41728) zero_region[idx] = 0.0f;
    }
    if (b == 0 && tid == 0) out[0] = 0.0f;
  }
  const float* W1 = z == 0 ? W1_0 : (z == 1 ? W1_1 : W1_2);
  const float* W2 = z == 0 ? W2_0 : (z == 1 ? W2_1 : W2_2);

  __shared__ float t[64][65];
  if (gy < 8) {
    const int k0 = gy * 64, n0 = gx * 64;
#pragma unroll
    for (int it = 0; it < 16; it++) {
      int r = it * 4 + (tid >> 6), c = tid & 63;
      t[r][c] = W1[(size_t)(k0 + r) * DHID + n0 + c];
    }
    __syncthreads();
    ushort_t* dst = w1t3 + (size_t)z * DHID * DIN;
#pragma unroll
    for (int it = 0; it < 16; it++) {
      int n = it * 4 + (tid >> 6), k = tid & 63;
      dst[(size_t)(n0 + n) * DIN + k0 + k] = (ushort_t)f2bf(t[k][n]);
    }
  } else {
    if (gx >= 2) return;
    const int k0 = (gy - 8) * 64, n0 = gx * 64;
#pragma unroll
    for (int it = 0; it < 16; it++) {
      int r = it * 4 + (tid >> 6), c = tid & 63;
      t[r][c] = W2[(size_t)(k0 + r) * DOUT + n0 + c];
    }
    __syncthreads();
    ushort_t* dst = w2t3 + (size_t)z * DOUT * DHID;
#pragma unroll
    for (int it = 0; it < 16; it++) {
      int n = it * 4 + (tid >> 6), k = tid & 63;
      dst[(size_t)(n0 + n) * DHID + k0 + k] = (ushort_t)f2bf(t[k][n]);
    }
  }
}

// ---------------------------------------------------------------------------
// Fused MLP v11 (all heads): y = (relu(x@W1+b1))@W2 + b2, bf16 y + col stats
// (stats from fp32 pre-quantization values). Block = 64 rows; 16 DMA-staged
// chunks of BK=32 (W 16 KB + x 8 KB per buffer, 2 x 24 KB LDS); 16
// MFMA/barrier. Phase 2 from padded LDS h-tile [64][264]. grid (128, 3).
// Round-9 lesson: acc growth lives in AGPRs; arch-side transients unchanged.
// ---------------------------------------------------------------------------
#define MLP_BUF 24576
__global__ __launch_bounds__(256, 2) void mlp_kernel(
    const float* __restrict__ x0, const float* __restrict__ x1,
    const float* __restrict__ x2,
    const ushort_t* __restrict__ w1t3,
    const float* __restrict__ b1_0, const float* __restrict__ b1_1,
    const float* __restrict__ b1_2,
    const ushort_t* __restrict__ w2t3,
    const float* __restrict__ b2_0, const float* __restrict__ b2_1,
    const float* __restrict__ b2_2,
    ushort_t* __restrict__ y3,
    float* __restrict__ colsum, float* __restrict__ colsumsq)
{
  const int z = blockIdx.y;
  const float* X  = z == 0 ? x0 : (z == 1 ? x1 : x2);
  const float* B1 = z == 0 ? b1_0 : (z == 1 ? b1_1 : b1_2);
  const float* B2 = z == 0 ? b2_0 : (z == 1 ? b2_1 : b2_2);
  const ushort_t* W1t = w1t3 + (size_t)z * DHID * DIN;
  const ushort_t* W2t = w2t3 + (size_t)z * DOUT * DHID;
  ushort_t* Y = y3 + (size_t)z * NROWS * DOUT;
  float* csum = colsum + z * DOUT;
  float* csq  = colsumsq + z * DOUT;

  __shared__ __align__(16) char lds[2 * MLP_BUF];  // 48 KB
  ushort_t* hs = (ushort_t*)lds;  // [64][264] = 33792 B (safe after final barrier)

  const int tid = threadIdx.x, lane = tid & 63, wave = tid >> 6;
  const int quad = lane >> 4, l16 = lane & 15;
  const int m0 = blockIdx.x * 64;

  // W1 DMA: 16 insts, j = wave*4+jj covers h-cols 16j..16j+15.
  const char* w1b = (const char*)W1t;
  const char* wsrc[4];
#pragma unroll
  for (int jj = 0; jj < 4; jj++)
    wsrc[jj] = w1b + (size_t)(16 * (wave * 4 + jj) + l16) * 1024 + quad * 16;
  // x DMA: 8 insts, j2 = wave*2+jj covers rows 8*j2..+8 (fp32, seg swizzle).
  const int row8 = lane >> 3, slot = lane & 7;
  const int gseg = (slot + row8) & 7;
  const char* xsrc[2];
#pragma unroll
  for (int jj = 0; jj < 2; jj++)
    xsrc[jj] = (const char*)X +
        (size_t)(m0 + 8 * (wave * 2 + jj) + row8) * 2048 + gseg * 16;

  f32x4 acc1[4][4] = {};  // [mt][ct]
  // prime chunk 0 -> buf 0
#pragma unroll
  for (int jj = 0; jj < 4; jj++)
    dma16(wsrc[jj], lds + (wave * 4 + jj) * 1024);
#pragma unroll
  for (int jj = 0; jj < 2; jj++)
    dma16(xsrc[jj], lds + 16384 + (wave * 2 + jj) * 1024);
  __syncthreads();

  for (int c = 0; c < 16; c++) {
    const int buf = c & 1;
    if (c + 1 < 16) {
      char* dst = lds + (buf ^ 1) * MLP_BUF;
#pragma unroll
      for (int jj = 0; jj < 4; jj++)
        dma16(wsrc[jj] + (c + 1) * 64, dst + (wave * 4 + jj) * 1024);
#pragma unroll
      for (int jj = 0; jj < 2; jj++)
        dma16(xsrc[jj] + (c + 1) * 128, dst + 16384 + (wave * 2 + jj) * 1024);
    }
    const char* wb = lds + buf * MLP_BUF;
    const char* xb = wb + 16384;
    bf16x8 a[4];
#pragma unroll
    for (int mt = 0; mt < 4; mt++) {
      const int r = mt * 16 + l16, r7 = r & 7;
      const int s0 = (2 * quad - r7) & 7, s1 = (2 * quad + 1 - r7) & 7;
      float4 v0 = *(const float4*)(xb + r * 128 + s0 * 16);
      float4 v1 = *(const float4*)(xb + r * 128 + s1 * 16);
      a[mt] = cvt8(v0, v1);
    }
    bf16x8 b[4];
#pragma unroll
    for (int ct = 0; ct < 4; ct++)
      b[ct] = *(const bf16x8*)(wb + (wave * 4 + ct) * 1024 + quad * 256 +
                               l16 * 16);
#pragma unroll
    for (int mt = 0; mt < 4; mt++)
#pragma unroll
      for (int ct = 0; ct < 4; ct++)
        acc1[mt][ct] = __builtin_amdgcn_mfma_f32_16x16x32_bf16(
            a[mt], b[ct], acc1[mt][ct], 0, 0, 0);
    __syncthreads();
  }

  // bulk-prefetch phase-2 W2 b-frags (fly during epilogue + barrier)
  bf16x8 b2f[2][8];  // [ct][kk]: out-cols wave*32+ct*16+l16
#pragma unroll
  for (int ct = 0; ct < 2; ct++)
#pragma unroll
    for (int kk = 0; kk < 8; kk++)
      b2f[ct][kk] = *(const bf16x8*)(W2t +
          (size_t)(wave * 32 + ct * 16 + l16) * DHID + kk * 32 + quad * 8);

  // phase-1 epilogue: bias + relu + bf16 -> hs (stride 264: 2-way = free)
#pragma unroll
  for (int ct = 0; ct < 4; ct++) {
    float bb = B1[wave * 64 + ct * 16 + l16];
#pragma unroll
    for (int mt = 0; mt < 4; mt++)
#pragma unroll
      for (int reg = 0; reg < 4; reg++) {
        float v = fmaxf(acc1[mt][ct][reg] + bb, 0.0f);
        hs[(mt * 16 + quad * 4 + reg) * 264 + wave * 64 + ct * 16 + l16] =
            (ushort_t)f2bf(v);
      }
  }
  __syncthreads();

  // phase 2: y[64 rows][wave*32..+32] = h @ W2 + b2
  f32x4 acc2[4][2] = {};
#pragma unroll
  for (int kk = 0; kk < 8; kk++) {
    bf16x8 a2[4];
#pragma unroll
    for (int mt = 0; mt < 4; mt++)
      a2[mt] = *(const bf16x8*)(hs + (mt * 16 + l16) * 264 + kk * 32 +
                                quad * 8);
#pragma unroll
    for (int mt = 0; mt < 4; mt++)
#pragma unroll
      for (int ct = 0; ct < 2; ct++)
        acc2[mt][ct] = __builtin_amdgcn_mfma_f32_16x16x32_bf16(
            a2[mt], b2f[ct][kk], acc2[mt][ct], 0, 0, 0);
  }

  // phase-2 epilogue: bias, bf16 y store, col stats (fp32 values)
#pragma unroll
  for (int ct = 0; ct < 2; ct++) {
    const int colo = wave * 32 + ct * 16 + l16;
    float bb = B2[colo];
    float cs = 0.0f, cq = 0.0f;
#pragma unroll
    for (int mt = 0; mt < 4; mt++)
#pragma unroll
      for (int reg = 0; reg < 4; reg++) {
        float v = acc2[mt][ct][reg] + bb;
        Y[(size_t)(m0 + mt * 16 + quad * 4 + reg) * DOUT + colo] =
            (ushort_t)f2bf(v);
        cs += v; cq += v * v;
      }
    cs += __shfl_xor(cs, 16, 64); cs += __shfl_xor(cs, 32, 64);
    cq += __shfl_xor(cq, 16, 64); cq += __shfl_xor(cq, 32, 64);
    if (lane < 16) {
      atomicAdd(&csum[colo], cs);
      atomicAdd(&csq[colo], cq);
    }
  }
}

// ---------------------------------------------------------------------------
// Whiten v11: wave-per-row, zero barriers, stats folded in; y3 is bf16.
// Each lane owns cols (lane, lane+64). grid 2048 x 256.
// ---------------------------------------------------------------------------
__global__ __launch_bounds__(256) void whiten_kernel(
    const ushort_t* __restrict__ y3,
    const float* __restrict__ colsum, const float* __restrict__ colsumsq,
    ushort_t* __restrict__ zB, ushort_t* __restrict__ zE,
    ushort_t* __restrict__ zF,
    ushort_t* __restrict__ zBs, ushort_t* __restrict__ zEs,
    float* __restrict__ pos)
{
  const int tid = threadIdx.x, lane = tid & 63, wave = tid >> 6;
  const int row = blockIdx.x * 4 + wave;
  const size_t base = (size_t)row * DOUT;
  const size_t hsz = (size_t)NROWS * DOUT;
  const int c0 = lane, c1 = lane + 64;

  float mu[3][2], isd[3][2];
#pragma unroll
  for (int h = 0; h < 3; h++) {
#pragma unroll
    for (int cc = 0; cc < 2; cc++) {
      const int idx = h * DOUT + (cc ? c1 : c0);
      float m = colsum[idx] * (1.0f / NROWS);
      float var = (colsumsq[idx] - (float)NROWS * m * m) *
                  (1.0f / (NROWS - 1));
      mu[h][cc] = m;
      isd[h][cc] = 1.0f / (sqrtf(fmaxf(var, 0.0f)) + 1e-5f);
    }
  }

  float vB0 = (bf2f(y3[base + c0])           - mu[0][0]) * isd[0][0];
  float vB1 = (bf2f(y3[base + c1])           - mu[0][1]) * isd[0][1];
  float vE0 = (bf2f(y3[base + hsz + c0])     - mu[1][0]) * isd[1][0];
  float vE1 = (bf2f(y3[base + hsz + c1])     - mu[1][1]) * isd[1][1];
  float vF0 = (bf2f(y3[base + 2 * hsz + c0]) - mu[2][0]) * isd[2][0];
  float vF1 = (bf2f(y3[base + 2 * hsz + c1]) - mu[2][1]) * isd[2][1];

  float nB = vB0 * vB0 + vB1 * vB1;
  float nE = vE0 * vE0 + vE1 * vE1;
  float nF = vF0 * vF0 + vF1 * vF1;
#pragma unroll
  for (int o = 1; o < 64; o <<= 1) {
    nB += __shfl_xor(nB, o, 64);
    nE += __shfl_xor(nE, o, 64);
    nF += __shfl_xor(nF, o, 64);
  }
  float iB = 1.0f / fmaxf(sqrtf(nB), 1e-12f);
  float iE = 1.0f / fmaxf(sqrtf(nE), 1e-12f);
  float iF = 1.0f / fmaxf(sqrtf(nF), 1e-12f);
  float zb0 = vB0 * iB, zb1 = vB1 * iB;
  float ze0 = vE0 * iE, ze1 = vE1 * iE;
  float zf0 = vF0 * iF, zf1 = vF1 * iF;

  zB[base + c0]  = (ushort_t)f2bf(zb0);
  zB[base + c1]  = (ushort_t)f2bf(zb1);
  zE[base + c0]  = (ushort_t)f2bf(ze0);
  zE[base + c1]  = (ushort_t)f2bf(ze1);
  zF[base + c0]  = (ushort_t)f2bf(zf0);
  zF[base + c1]  = (ushort_t)f2bf(zf1);
  zBs[base + c0] = (ushort_t)f2bf(zb0 * LOG2E);
  zBs[base + c1] = (ushort_t)f2bf(zb1 * LOG2E);
  zEs[base + c0] = (ushort_t)f2bf(ze0 * LOG2E);
  zEs[base + c1] = (ushort_t)f2bf(ze1 * LOG2E);

  float pBE = zb0 * ze0 + zb1 * ze1;
  float pBF = zb0 * zf0 + zb1 * zf1;
  float pEF = ze0 * zf0 + ze1 * zf1;
#pragma unroll
  for (int o = 1; o < 64; o <<= 1) {
    pBE += __shfl_xor(pBE, o, 64);
    pBF += __shfl_xor(pBF, o, 64);
    pEF += __shfl_xor(pEF, o, 64);
  }
  if (lane == 0) {
    pos[row]             = pBE;
    pos[NROWS + row]     = pBF;
    pos[2 * NROWS + row] = pEF;
  }
}

// ---------------------------------------------------------------------------
// Gram (round-8 known-good, untouched): rowsum_i += sum_j exp2(Us_i . V_j).
// Async LDS staging, 32-col chunks, G_NCH=32, grid (32, 8, 5) = 1280 blocks.
// NOTE: do NOT widen the per-barrier stage (round-9 spill regression).
// ---------------------------------------------------------------------------
#define G_CH  32
#define G_NCH 32
__global__ __launch_bounds__(256, 3) void gram_kernel(
    const ushort_t* __restrict__ zB, const ushort_t* __restrict__ zE,
    const ushort_t* __restrict__ zF,
    const ushort_t* __restrict__ zBs, const ushort_t* __restrict__ zEs,
    float* __restrict__ rowsum)
{
  const ushort_t *U, *V;
  float* rs;
  switch (blockIdx.z) {
    case 0:  U = zBs; V = zB; rs = rowsum;             break;
    case 1:  U = zEs; V = zE; rs = rowsum + NROWS;     break;
    case 2:  U = zBs; V = zE; rs = rowsum + 2 * NROWS; break;
    case 3:  U = zBs; V = zF; rs = rowsum + 3 * NROWS; break;
    default: U = zEs; V = zF; rs = rowsum + 4 * NROWS; break;
  }

  const int tid = threadIdx.x, lane = tid & 63, wave = tid >> 6;
  const int quad = lane >> 4, l16 = lane & 15;
  const int m0 = blockIdx.x * 256 + wave * 64;
  const int col0 = blockIdx.y * (G_CH * G_NCH);

  __shared__ __align__(16) ushort_t sbuf[2][4096];

  const ushort_t* ua = U + (size_t)(m0 + l16) * DOUT + quad * 8;
  bf16x8 a[4][4];
#pragma unroll
  for (int rt = 0; rt < 4; rt++)
#pragma unroll
    for (int ki = 0; ki < 4; ki++)
      a[rt][ki] = *(const bf16x8*)(ua + rt * 16 * DOUT + ki * 32);

  const char* Vb = (const char*)V;
  const int r_ = lane & 31, hi_ = lane >> 5;
  const int s0 = 4 * wave + hi_, s1 = 4 * wave + 2 + hi_;
  const char* g0 = Vb + (size_t)(col0 + r_) * 256 + (s0 >> 2) * 64 + (s0 & 3) * 16;
  const char* g1 = Vb + (size_t)(col0 + r_) * 256 + (s1 >> 2) * 64 + (s1 & 3) * 16;

  float rsum[4][4] = {};
  const f32x4 zero = {0.0f, 0.0f, 0.0f, 0.0f};

  dma16(g0, &sbuf[0][(2 * wave) * 512]);
  dma16(g1, &sbuf[0][(2 * wave + 1) * 512]);
  __syncthreads();

  for (int c = 0; c < G_NCH; c++) {
    const int buf = c & 1;
    if (c + 1 < G_NCH) {
      const size_t go = (size_t)(c + 1) * 8192;
      dma16(g0 + go, &sbuf[buf ^ 1][(2 * wave) * 512]);
      dma16(g1 + go, &sbuf[buf ^ 1][(2 * wave + 1) * 512]);
    }
    const char* sb = (const char*)&sbuf[buf][0];
    bf16x8 b[4][2];
#pragma unroll
    for (int ki = 0; ki < 4; ki++)
#pragma unroll
      for (int ct = 0; ct < 2; ct++)
        b[ki][ct] = *(const bf16x8*)(sb + (ki * 4 + quad) * 512 +
                                     (ct * 16 + l16) * 16);
    f32x4 acc[4][2];
#pragma unroll
    for (int ki = 0; ki < 4; ki++)
#pragma unroll
      for (int rt = 0; rt < 4; rt++)
#pragma unroll
        for (int ct = 0; ct < 2; ct++)
          acc[rt][ct] = __builtin_amdgcn_mfma_f32_16x16x32_bf16(
              a[rt][ki], b[ki][ct], ki == 0 ? zero : acc[rt][ct], 0, 0, 0);
#pragma unroll
    for (int rt = 0; rt < 4; rt++)
#pragma unroll
      for (int reg = 0; reg < 4; reg++)
        rsum[rt][reg] += FAST_EXP2(acc[rt][0][reg]) + FAST_EXP2(acc[rt][1][reg]);
    __syncthreads();
  }

#pragma unroll
  for (int rt = 0; rt < 4; rt++)
#pragma unroll
    for (int reg = 0; reg < 4; reg++) {
      float s = rsum[rt][reg];
      s += __shfl_xor(s, 1, 64);
      s += __shfl_xor(s, 2, 64);
      s += __shfl_xor(s, 4, 64);
      s += __shfl_xor(s, 8, 64);
      if (l16 == 0)
        atomicAdd(&rs[m0 + rt * 16 + quad * 4 + reg], s);
    }
}

// ---------------------------------------------------------------------------
// Loss v11: 32 blocks x 256 threads, one row each; block partial ->
// atomicAdd into d_out (zero-initialized by prep_w).
// ---------------------------------------------------------------------------
__global__ __launch_bounds__(256) void loss_kernel(
    const float* __restrict__ rowsum, const float* __restrict__ pos,
    float* __restrict__ out)
{
  const float* sB  = rowsum;
  const float* sE  = rowsum + NROWS;
  const float* cBE = rowsum + 2 * NROWS;
  const float* cBF = rowsum + 3 * NROWS;
  const float* cEF = rowsum + 4 * NROWS;
  const float* pBE = pos;
  const float* pBF = pos + NROWS;
  const float* pEF = pos + 2 * NROWS;

  const int i = blockIdx.x * 256 + threadIdx.x;
  const float corr = 1.0f - expf(1.0f);
  float selB = sB[i] + corr;
  float selE = sE[i] + corr;
  float local = __logf(selB + cBE[i]) - pBE[i];
  local += __logf(selB + cBF[i]) - pBF[i];
  local += __logf(selE + cEF[i]) - pEF[i];

  __shared__ float red[4];
#pragma unroll
  for (int o = 32; o > 0; o >>= 1) local += __shfl_down(local, o, 64);
  int lane = threadIdx.x & 63, wv = threadIdx.x >> 6;
  if (lane == 0) red[wv] = local;
  __syncthreads();
  if (threadIdx.x == 0) {
    float t = red[0] + red[1] + red[2] + red[3];
    atomicAdd(out, t * (1.0f / (3.0f * (float)NROWS)));
  }
}

// ---------------------------------------------------------------------------
extern "C" void kernel_launch(void* const* d_in, const int* in_sizes, int n_in,
                              void* d_out, int out_size, void* d_ws, size_t ws_size,
                              hipStream_t stream)
{
  const float* xs[3] = {(const float*)d_in[0], (const float*)d_in[1], (const float*)d_in[2]};
  const float* W1[3] = {(const float*)d_in[3], (const float*)d_in[7],  (const float*)d_in[11]};
  const float* b1[3] = {(const float*)d_in[4], (const float*)d_in[8],  (const float*)d_in[12]};
  const float* W2[3] = {(const float*)d_in[5], (const float*)d_in[9],  (const float*)d_in[13]};
  const float* b2[3] = {(const float*)d_in[6], (const float*)d_in[10], (const float*)d_in[14]};

  float* ws = (float*)d_ws;
  // workspace layout (float offsets):
  float* colsum   = ws;            // 384   [zeroed by prep_w]
  float* colsumsq = ws + 384;      // 384   [zeroed by prep_w]
  float* rowsum   = ws + 768;      // 5*8192 [zeroed by prep_w]
  float* pos      = ws + 42496;    // 3*8192 -> ends 67072
  ushort_t* w1t3 = (ushort_t*)(ws + 67072);    // 3*256*512 bf16 = 196608 fl
  ushort_t* w2t3 = (ushort_t*)(ws + 263680);   // 3*128*256 bf16 = 49152 fl
  ushort_t* y3b  = (ushort_t*)(ws + 312832);   // 3*8192*128 bf16 = 1572864 fl
  ushort_t* zB   = (ushort_t*)(ws + 1885696);  // 5 x 8192*128 bf16
  ushort_t* zE   = zB  + (size_t)NROWS * DOUT;
  ushort_t* zF   = zE  + (size_t)NROWS * DOUT;
  ushort_t* zBs  = zF  + (size_t)NROWS * DOUT;
  ushort_t* zEs  = zBs + (size_t)NROWS * DOUT;
  // peak ws usage: 4,507,136 floats = 18.0 MB

  prep_w_kernel<<<dim3(4, 12, 3), 256, 0, stream>>>(
      W1[0], W1[1], W1[2], W2[0], W2[1], W2[2], w1t3, w2t3, ws, (float*)d_out);
  mlp_kernel<<<dim3(128, 3), 256, 0, stream>>>(
      xs[0], xs[1], xs[2], w1t3, b1[0], b1[1], b1[2],
      w2t3, b2[0], b2[1], b2[2], y3b, colsum, colsumsq);
  whiten_kernel<<<2048, 256, 0, stream>>>(
      y3b, colsum, colsumsq, zB, zE, zF, zBs, zEs, pos);
  gram_kernel<<<dim3(32, 8, 5), 256, 0, stream>>>(zB, zE, zF, zBs, zEs, rowsum);
  loss_kernel<<<32, 256, 0, stream>>>(rowsum, pos, (float*)d_out);
}